// Round 10
// baseline (140.815 us; speedup 1.0000x reference)
//
#include <hip/hip_runtime.h>
#include <hip/hip_bf16.h>

using bf16x8 = __attribute__((ext_vector_type(8))) short;   // 8 bf16 (16 B)
using f32x4  = __attribute__((ext_vector_type(4))) float;   // MFMA C/D frag

#define NN 1024
#define DD 128

__device__ __forceinline__ short bf16b(float f) {
    __hip_bfloat16 t = __float2bfloat16(f);
    return *(short*)&t;
}

__device__ __forceinline__ bf16x8 cvt8(const float* __restrict__ p) {
    float4 a = *(const float4*)p;
    float4 b = *(const float4*)(p + 4);
    bf16x8 r;
    r[0] = bf16b(a.x); r[1] = bf16b(a.y); r[2] = bf16b(a.z); r[3] = bf16b(a.w);
    r[4] = bf16b(b.x); r[5] = bf16b(b.y); r[6] = bf16b(b.z); r[7] = bf16b(b.w);
    return r;
}

// ---- kernel 1 (MFMA): h=S@Win^T -> M(bf16); valT=((S@Wout^T)*g)^T (bf16) ----
// grid (4 col-quarters, 64 row-tiles, 2 b) = 512 blocks, 1 wave each.
__global__ __launch_bounds__(64) void prep_kernel(
    const float* __restrict__ states, const float* __restrict__ gates,
    const float* __restrict__ W_in, const float* __restrict__ W_out,
    __hip_bfloat16* __restrict__ M_bf, __hip_bfloat16* __restrict__ valT)
{
    __shared__ __align__(16) short s_m[16][32];    // [n_loc][d_loc]
    __shared__ __align__(16) short s_vT[32][16];   // [d_loc][n_loc]

    const int tid = threadIdx.x;
    const int row_a = tid & 15, kg = tid >> 4;
    const int c0 = blockIdx.x * 32;
    const int n0 = blockIdx.y * 16;
    const int b  = blockIdx.z;

    const float* A = states + ((size_t)b * NN + n0) * DD;

    f32x4 accH[2], accV[2];
    #pragma unroll
    for (int cp = 0; cp < 2; ++cp) {
        accH[cp] = (f32x4){0.f, 0.f, 0.f, 0.f};
        accV[cp] = (f32x4){0.f, 0.f, 0.f, 0.f};
    }

    #pragma unroll
    for (int ks = 0; ks < 4; ++ks) {
        int koff = (ks * 4 + kg) * 8;
        bf16x8 a = cvt8(A + row_a * DD + koff);
        #pragma unroll
        for (int cp = 0; cp < 2; ++cp) {
            int d = c0 + cp * 16 + row_a;
            bf16x8 b1 = cvt8(W_in  + d * DD + koff);
            bf16x8 b2 = cvt8(W_out + d * DD + koff);
            accH[cp] = __builtin_amdgcn_mfma_f32_16x16x32_bf16(a, b1, accH[cp], 0, 0, 0);
            accV[cp] = __builtin_amdgcn_mfma_f32_16x16x32_bf16(a, b2, accV[cp], 0, 0, 0);
        }
    }

    float g[4];
    #pragma unroll
    for (int q = 0; q < 4; ++q) g[q] = gates[b * NN + n0 + kg * 4 + q];

    const bool odd = (row_a & 1) != 0;
    #pragma unroll
    for (int cp = 0; cp < 2; ++cp) {
        #pragma unroll
        for (int q = 0; q < 4; ++q) {
            float hm = accH[cp][q] + 1e-8f;       // my (h+eps); d parity = lane parity
            float hp = __shfl_xor(hm, 1);         // pair partner (adjacent d / lane)
            float x = odd ? hp : hm;
            float y = odd ? hm : hp;
            float r2 = x * x + y * y;
            float out;
            if (r2 > 0.f) out = (odd ? y : x) * rsqrtf(r2);
            else          out = odd ? 0.f : 1.f;  // atan2(0,0)=0 -> cos=1,sin=0
            s_m[kg * 4 + q][cp * 16 + row_a] = bf16b(out);
            s_vT[cp * 16 + row_a][kg * 4 + q] = bf16b(accV[cp][q] * g[q]);
        }
    }
    __syncthreads();

    {   // M tile: 16 rows x 32 cols, 16B packed stores
        int r = tid >> 2, seg = tid & 3;
        bf16x8 v = *(const bf16x8*)&s_m[r][seg * 8];
        *(bf16x8*)(M_bf + ((size_t)b * NN + n0 + r) * DD + c0 + seg * 8) = v;
    }
    {   // valT tile: 32 d-rows x 16 n, 16B packed stores
        int d = tid >> 1, half = tid & 1;
        bf16x8 v = *(const bf16x8*)&s_vT[d][half * 8];
        *(bf16x8*)(valT + ((size_t)b * DD + c0 + d) * NN + n0 + half * 8) = v;
    }
}

// ---- kernel 2 (fused + in-kernel finalize): 16i x 128j per block ----
// grid (64 it, 8 jq, 2 b) = 1024 blocks, 256 thr. jq-siblings spaced 64 apart
// -> same XCD under round-robin dispatch (part slabs stay in one L2).
// Last of the 8 jq blocks per (it,b) (device-scope counter) reduces the 8
// part slabs + rowsums and writes field. No separate reduce dispatch.
__global__ __launch_bounds__(256, 4) void fused_kernel(
    const __hip_bfloat16* __restrict__ M_bf,
    const __hip_bfloat16* __restrict__ valT,
    const float* __restrict__ r_acc,
    const float* __restrict__ gates,
    const float* __restrict__ cond_ptr,
    float* __restrict__ r_out,
    __hip_bfloat16* __restrict__ part,
    float* __restrict__ part_rs,
    int* __restrict__ cnt,
    float* __restrict__ field)
{
    __shared__ __align__(16) short s_cpl[16][136];   // [i_loc][j_loc]
    __shared__ float s_rs[16][4];                    // [i_loc][wave]
    __shared__ int s_done;

    const int tid = threadIdx.x;
    const int l = tid & 63, w = tid >> 6;
    const int row_a = l & 15, kg = l >> 4;
    const int it = blockIdx.x;
    const int i0 = it * 16;
    const int jq = blockIdx.y;
    const int j0 = jq * 128;
    const int b  = blockIdx.z;

    const bf16x8* Mv = (const bf16x8*)(M_bf + (size_t)b * NN * DD);
    const bf16x8* Vv = (const bf16x8*)(valT + (size_t)b * DD * NN);

    // ---- M fragment loads FIRST (L2-resident; oldest in vmcnt queue) ----
    bf16x8 aF[4], bF[4][2];
    #pragma unroll
    for (int ks = 0; ks < 4; ++ks) {
        aF[ks] = Mv[(size_t)(i0 + row_a) * 16 + ks * 4 + kg];
        #pragma unroll
        for (int cp = 0; cp < 2; ++cp)
            bF[ks][cp] = Mv[(size_t)(j0 + w * 32 + cp * 16 + row_a) * 16 + ks * 4 + kg];
    }

    // ---- r_acc loads (HBM, newest in queue -> overlap with S phase) ----
    const size_t robase = (size_t)b * NN * NN;
    float ra[4][2];
    #pragma unroll
    for (int q = 0; q < 4; ++q) {
        const int i = i0 + kg * 4 + q;
        #pragma unroll
        for (int cp = 0; cp < 2; ++cp)
            ra[q][cp] = r_acc[robase + (size_t)i * NN + j0 + w * 32 + cp * 16 + row_a];
    }

    const float cond = fminf(fmaxf(cond_ptr[0], -5.f), 5.f);
    float g_i[4], g_j[2];
    #pragma unroll
    for (int q = 0; q < 4; ++q) g_i[q] = gates[(size_t)b * NN + i0 + kg * 4 + q];
    #pragma unroll
    for (int cp = 0; cp < 2; ++cp) g_j[cp] = gates[(size_t)b * NN + j0 + w * 32 + cp * 16 + row_a];

    // ---- S phase MFMAs (wait only on M loads) ----
    f32x4 acc[2];
    acc[0] = (f32x4){0.f, 0.f, 0.f, 0.f};
    acc[1] = (f32x4){0.f, 0.f, 0.f, 0.f};
    #pragma unroll
    for (int ks = 0; ks < 4; ++ks) {
        #pragma unroll
        for (int cp = 0; cp < 2; ++cp)
            acc[cp] = __builtin_amdgcn_mfma_f32_16x16x32_bf16(aF[ks], bF[ks][cp], acc[cp], 0, 0, 0);
    }

    // ---- epilogue: r_out, coupling -> LDS, rowsum partials ----
    float rs[4] = {0.f, 0.f, 0.f, 0.f};
    #pragma unroll
    for (int q = 0; q < 4; ++q) {
        const int i = i0 + kg * 4 + q;               // C/D row = kg*4+q [m89]
        const float gi = g_i[q];
        #pragma unroll
        for (int cp = 0; cp < 2; ++cp) {
            const int jl = w * 32 + cp * 16 + row_a;
            const int j  = j0 + jl;                  // C/D col = lane&15
            float s  = acc[cp][q] * (1.f / 64.f);
            float rn = fminf(fmaxf(0.7f * ra[q][cp] + 0.3f * s, -2.f), 2.f);
            r_out[robase + (size_t)i * NN + j] = rn;
            float cpl = (i == j) ? 0.f
                        : (1.f / (1.f + __expf(-cond * rn))) * gi * g_j[cp];
            rs[q] += cpl;
            s_cpl[kg * 4 + q][jl] = bf16b(cpl);
        }
    }

    #pragma unroll
    for (int q = 0; q < 4; ++q) {
        float v = rs[q];
        v += __shfl_xor(v, 1);
        v += __shfl_xor(v, 2);
        v += __shfl_xor(v, 4);
        v += __shfl_xor(v, 8);
        if (row_a == 0) s_rs[kg * 4 + q][w] = v;
    }
    __syncthreads();

    // ---- PV: wave w owns d-quarter w*32..+31; full 16x128 cpl from LDS ----
    f32x4 pacc[2];
    pacc[0] = (f32x4){0.f, 0.f, 0.f, 0.f};
    pacc[1] = (f32x4){0.f, 0.f, 0.f, 0.f};
    #pragma unroll
    for (int ks2 = 0; ks2 < 4; ++ks2) {
        bf16x8 a = *(const bf16x8*)&s_cpl[row_a][(ks2 * 4 + kg) * 8];
        #pragma unroll
        for (int dt = 0; dt < 2; ++dt) {
            int d = w * 32 + dt * 16 + row_a;
            bf16x8 bb = Vv[(size_t)d * (NN / 8) + (j0 >> 3) + ks2 * 4 + kg];
            pacc[dt] = __builtin_amdgcn_mfma_f32_16x16x32_bf16(a, bb, pacc[dt], 0, 0, 0);
        }
    }

    __hip_bfloat16* pb = part + ((size_t)jq * 2 + b) * NN * DD;
    #pragma unroll
    for (int dt = 0; dt < 2; ++dt) {
        #pragma unroll
        for (int q = 0; q < 4; ++q) {
            int ii = i0 + kg * 4 + q;
            int d  = w * 32 + dt * 16 + row_a;
            pb[(size_t)ii * DD + d] = __float2bfloat16(pacc[dt][q]);
        }
    }

    if (tid < 16)
        part_rs[((size_t)jq * 2 + b) * NN + i0 + tid] =
            s_rs[tid][0] + s_rs[tid][1] + s_rs[tid][2] + s_rs[tid][3];

    // ---- arrival counter: last of 8 jq siblings finalizes this row-tile ----
    __syncthreads();                      // drain this block's global stores
    if (tid == 0) {
        __threadfence();                  // release: part/part_rs visible device-wide
        s_done = (atomicAdd(&cnt[b * 64 + it], 1) == 7);
    }
    __syncthreads();
    if (s_done) {
        __threadfence();                  // acquire: invalidate stale cache lines
        const int row = tid >> 4;         // 0..15
        const int d8  = (tid & 15) * 8;   // 8 consecutive d
        const int i   = i0 + row;
        float a8[8] = {0.f, 0.f, 0.f, 0.f, 0.f, 0.f, 0.f, 0.f};
        float rsum = 1e-8f;
        #pragma unroll
        for (int q = 0; q < 8; ++q) {     // sum jq ascending (matches old reduce)
            const size_t slab = (size_t)q * 2 + b;
            uint4 u = *(const uint4*)(part + slab * NN * DD + (size_t)i * DD + d8);
            a8[0] += __uint_as_float(u.x << 16);
            a8[1] += __uint_as_float(u.x & 0xffff0000u);
            a8[2] += __uint_as_float(u.y << 16);
            a8[3] += __uint_as_float(u.y & 0xffff0000u);
            a8[4] += __uint_as_float(u.z << 16);
            a8[5] += __uint_as_float(u.z & 0xffff0000u);
            a8[6] += __uint_as_float(u.w << 16);
            a8[7] += __uint_as_float(u.w & 0xffff0000u);
            rsum  += part_rs[slab * NN + i];
        }
        float inv = 1.0f / rsum;
        float4 o0 = {a8[0] * inv, a8[1] * inv, a8[2] * inv, a8[3] * inv};
        float4 o1 = {a8[4] * inv, a8[5] * inv, a8[6] * inv, a8[7] * inv};
        float* fp = field + ((size_t)b * NN + i) * DD + d8;
        *(float4*)fp       = o0;
        *(float4*)(fp + 4) = o1;
    }
}

// ---------------- launch ----------------
extern "C" void kernel_launch(void* const* d_in, const int* in_sizes, int n_in,
                              void* d_out, int out_size, void* d_ws, size_t ws_size,
                              hipStream_t stream) {
    const float* states = (const float*)d_in[0];
    const float* gates  = (const float*)d_in[1];
    const float* r_acc  = (const float*)d_in[2];
    const float* W_in   = (const float*)d_in[3];
    const float* W_out  = (const float*)d_in[4];
    const float* cond   = (const float*)d_in[5];

    float* field = (float*)d_out;                 // (2,1024,128)
    float* r_out = field + 2 * NN * DD;           // (2,1024,1024)

    char* ws = (char*)d_ws;
    __hip_bfloat16* M_bf    = (__hip_bfloat16*)ws;                   // 512 KB @ 0
    __hip_bfloat16* valT    = (__hip_bfloat16*)(ws + (512 << 10));   // 512 KB @ 512K
    __hip_bfloat16* part    = (__hip_bfloat16*)(ws + (1 << 20));     // 4 MB  @ 1M
    float*          part_rs = (float*)(ws + (5 << 20));              // 64 KB @ 5M
    int*            cnt     = (int*)(ws + (6 << 20));                // 512 B @ 6M

    hipMemsetAsync(cnt, 0, 128 * sizeof(int), stream);
    hipLaunchKernelGGL(prep_kernel, dim3(4, 64, 2), dim3(64), 0, stream,
                       states, gates, W_in, W_out, M_bf, valT);
    hipLaunchKernelGGL(fused_kernel, dim3(64, 8, 2), dim3(256), 0, stream,
                       M_bf, valT, r_acc, gates, cond, r_out, part, part_rs,
                       cnt, field);
}

// Round 11
// 95.086 us; speedup vs baseline: 1.4809x; 1.4809x over previous
//
#include <hip/hip_runtime.h>
#include <hip/hip_bf16.h>

using bf16x8 = __attribute__((ext_vector_type(8))) short;   // 8 bf16 (16 B)
using f32x4  = __attribute__((ext_vector_type(4))) float;   // MFMA C/D frag

#define NN 1024
#define DD 128

__device__ __forceinline__ short bf16b(float f) {
    __hip_bfloat16 t = __float2bfloat16(f);
    return *(short*)&t;
}

__device__ __forceinline__ bf16x8 cvt8(const float* __restrict__ p) {
    float4 a = *(const float4*)p;
    float4 b = *(const float4*)(p + 4);
    bf16x8 r;
    r[0] = bf16b(a.x); r[1] = bf16b(a.y); r[2] = bf16b(a.z); r[3] = bf16b(a.w);
    r[4] = bf16b(b.x); r[5] = bf16b(b.y); r[6] = bf16b(b.z); r[7] = bf16b(b.w);
    return r;
}

// ---- kernel 1 (MFMA): h=S@Win^T -> M(bf16); valT=((S@Wout^T)*g)^T (bf16) ----
// grid (4 col-quarters, 64 row-tiles, 2 b) = 512 blocks, 1 wave each.
__global__ __launch_bounds__(64) void prep_kernel(
    const float* __restrict__ states, const float* __restrict__ gates,
    const float* __restrict__ W_in, const float* __restrict__ W_out,
    __hip_bfloat16* __restrict__ M_bf, __hip_bfloat16* __restrict__ valT)
{
    __shared__ __align__(16) short s_m[16][32];    // [n_loc][d_loc]
    __shared__ __align__(16) short s_vT[32][16];   // [d_loc][n_loc]

    const int tid = threadIdx.x;
    const int row_a = tid & 15, kg = tid >> 4;
    const int c0 = blockIdx.x * 32;
    const int n0 = blockIdx.y * 16;
    const int b  = blockIdx.z;

    const float* A = states + ((size_t)b * NN + n0) * DD;

    f32x4 accH[2], accV[2];
    #pragma unroll
    for (int cp = 0; cp < 2; ++cp) {
        accH[cp] = (f32x4){0.f, 0.f, 0.f, 0.f};
        accV[cp] = (f32x4){0.f, 0.f, 0.f, 0.f};
    }

    #pragma unroll
    for (int ks = 0; ks < 4; ++ks) {
        int koff = (ks * 4 + kg) * 8;
        bf16x8 a = cvt8(A + row_a * DD + koff);
        #pragma unroll
        for (int cp = 0; cp < 2; ++cp) {
            int d = c0 + cp * 16 + row_a;
            bf16x8 b1 = cvt8(W_in  + d * DD + koff);
            bf16x8 b2 = cvt8(W_out + d * DD + koff);
            accH[cp] = __builtin_amdgcn_mfma_f32_16x16x32_bf16(a, b1, accH[cp], 0, 0, 0);
            accV[cp] = __builtin_amdgcn_mfma_f32_16x16x32_bf16(a, b2, accV[cp], 0, 0, 0);
        }
    }

    float g[4];
    #pragma unroll
    for (int q = 0; q < 4; ++q) g[q] = gates[b * NN + n0 + kg * 4 + q];

    const bool odd = (row_a & 1) != 0;
    #pragma unroll
    for (int cp = 0; cp < 2; ++cp) {
        #pragma unroll
        for (int q = 0; q < 4; ++q) {
            float hm = accH[cp][q] + 1e-8f;       // my (h+eps); d parity = lane parity
            float hp = __shfl_xor(hm, 1);         // pair partner (adjacent d / lane)
            float x = odd ? hp : hm;
            float y = odd ? hm : hp;
            float r2 = x * x + y * y;
            float out;
            if (r2 > 0.f) out = (odd ? y : x) * rsqrtf(r2);
            else          out = odd ? 0.f : 1.f;  // atan2(0,0)=0 -> cos=1,sin=0
            s_m[kg * 4 + q][cp * 16 + row_a] = bf16b(out);
            s_vT[cp * 16 + row_a][kg * 4 + q] = bf16b(accV[cp][q] * g[q]);
        }
    }
    __syncthreads();

    {   // M tile: 16 rows x 32 cols, 16B packed stores
        int r = tid >> 2, seg = tid & 3;
        bf16x8 v = *(const bf16x8*)&s_m[r][seg * 8];
        *(bf16x8*)(M_bf + ((size_t)b * NN + n0 + r) * DD + c0 + seg * 8) = v;
    }
    {   // valT tile: 32 d-rows x 16 n, 16B packed stores
        int d = tid >> 1, half = tid & 1;
        bf16x8 v = *(const bf16x8*)&s_vT[d][half * 8];
        *(bf16x8*)(valT + ((size_t)b * DD + c0 + d) * NN + n0 + half * 8) = v;
    }
}

// ---- kernel 2 (fused): 16i x 128j per block ----
// grid (8 jq, 64 it, 2 b) = 1024 blocks, 256 thr (4 waves).
// Order: M frags -> regs (L2, oldest in vmcnt queue), r_acc -> regs (HBM,
// newest; latency hides under MFMAs), S-MFMA, epilogue, cpl->LDS, PV-MFMA.
__global__ __launch_bounds__(256, 4) void fused_kernel(
    const __hip_bfloat16* __restrict__ M_bf,
    const __hip_bfloat16* __restrict__ valT,
    const float* __restrict__ r_acc,
    const float* __restrict__ gates,
    const float* __restrict__ cond_ptr,
    float* __restrict__ r_out,
    __hip_bfloat16* __restrict__ part,
    float* __restrict__ part_rs)
{
    __shared__ __align__(16) short s_cpl[16][136];   // [i_loc][j_loc]
    __shared__ float s_rs[16][4];                    // [i_loc][wave]

    const int tid = threadIdx.x;
    const int l = tid & 63, w = tid >> 6;
    const int row_a = l & 15, kg = l >> 4;
    const int jq = blockIdx.x;
    const int j0 = jq * 128;
    const int i0 = blockIdx.y * 16;
    const int b  = blockIdx.z;

    const bf16x8* Mv = (const bf16x8*)(M_bf + (size_t)b * NN * DD);
    const bf16x8* Vv = (const bf16x8*)(valT + (size_t)b * DD * NN);

    // ---- M fragment loads FIRST (L2-resident; oldest in vmcnt queue) ----
    bf16x8 aF[4], bF[4][2];
    #pragma unroll
    for (int ks = 0; ks < 4; ++ks) {
        aF[ks] = Mv[(size_t)(i0 + row_a) * 16 + ks * 4 + kg];
        #pragma unroll
        for (int cp = 0; cp < 2; ++cp)
            bF[ks][cp] = Mv[(size_t)(j0 + w * 32 + cp * 16 + row_a) * 16 + ks * 4 + kg];
    }

    // ---- r_acc loads (HBM, newest in queue -> overlap with S phase) ----
    const size_t robase = (size_t)b * NN * NN;
    float ra[4][2];
    #pragma unroll
    for (int q = 0; q < 4; ++q) {
        const int i = i0 + kg * 4 + q;
        #pragma unroll
        for (int cp = 0; cp < 2; ++cp)
            ra[q][cp] = r_acc[robase + (size_t)i * NN + j0 + w * 32 + cp * 16 + row_a];
    }

    const float cond = fminf(fmaxf(cond_ptr[0], -5.f), 5.f);
    float g_i[4], g_j[2];
    #pragma unroll
    for (int q = 0; q < 4; ++q) g_i[q] = gates[(size_t)b * NN + i0 + kg * 4 + q];
    #pragma unroll
    for (int cp = 0; cp < 2; ++cp) g_j[cp] = gates[(size_t)b * NN + j0 + w * 32 + cp * 16 + row_a];

    // ---- S phase MFMAs (wait only on M loads) ----
    f32x4 acc[2];
    acc[0] = (f32x4){0.f, 0.f, 0.f, 0.f};
    acc[1] = (f32x4){0.f, 0.f, 0.f, 0.f};
    #pragma unroll
    for (int ks = 0; ks < 4; ++ks) {
        #pragma unroll
        for (int cp = 0; cp < 2; ++cp)
            acc[cp] = __builtin_amdgcn_mfma_f32_16x16x32_bf16(aF[ks], bF[ks][cp], acc[cp], 0, 0, 0);
    }

    // ---- epilogue: r_out, coupling -> LDS, rowsum partials ----
    float rs[4] = {0.f, 0.f, 0.f, 0.f};
    #pragma unroll
    for (int q = 0; q < 4; ++q) {
        const int i = i0 + kg * 4 + q;               // C/D row = kg*4+q [m89]
        const float gi = g_i[q];
        #pragma unroll
        for (int cp = 0; cp < 2; ++cp) {
            const int jl = w * 32 + cp * 16 + row_a;
            const int j  = j0 + jl;                  // C/D col = lane&15
            float s  = acc[cp][q] * (1.f / 64.f);
            float rn = fminf(fmaxf(0.7f * ra[q][cp] + 0.3f * s, -2.f), 2.f);
            r_out[robase + (size_t)i * NN + j] = rn;
            float cpl = (i == j) ? 0.f
                        : (1.f / (1.f + __expf(-cond * rn))) * gi * g_j[cp];
            rs[q] += cpl;
            s_cpl[kg * 4 + q][jl] = bf16b(cpl);
        }
    }

    // rowsum partials: reduce over the 16 row_a lanes
    #pragma unroll
    for (int q = 0; q < 4; ++q) {
        float v = rs[q];
        v += __shfl_xor(v, 1);
        v += __shfl_xor(v, 2);
        v += __shfl_xor(v, 4);
        v += __shfl_xor(v, 8);
        if (row_a == 0) s_rs[kg * 4 + q][w] = v;
    }
    __syncthreads();

    // ---- PV: wave w owns d-quarter w*32..+31; full 16x128 cpl from LDS ----
    f32x4 pacc[2];
    pacc[0] = (f32x4){0.f, 0.f, 0.f, 0.f};
    pacc[1] = (f32x4){0.f, 0.f, 0.f, 0.f};
    #pragma unroll
    for (int ks2 = 0; ks2 < 4; ++ks2) {
        bf16x8 a = *(const bf16x8*)&s_cpl[row_a][(ks2 * 4 + kg) * 8];
        #pragma unroll
        for (int dt = 0; dt < 2; ++dt) {
            int d = w * 32 + dt * 16 + row_a;
            bf16x8 bb = Vv[(size_t)d * (NN / 8) + (j0 >> 3) + ks2 * 4 + kg];
            pacc[dt] = __builtin_amdgcn_mfma_f32_16x16x32_bf16(a, bb, pacc[dt], 0, 0, 0);
        }
    }

    __hip_bfloat16* pb = part + ((size_t)jq * 2 + b) * NN * DD;
    #pragma unroll
    for (int dt = 0; dt < 2; ++dt) {
        #pragma unroll
        for (int q = 0; q < 4; ++q) {
            int ii = i0 + kg * 4 + q;
            int d  = w * 32 + dt * 16 + row_a;
            pb[(size_t)ii * DD + d] = __float2bfloat16(pacc[dt][q]);
        }
    }

    if (tid < 16)
        part_rs[((size_t)jq * 2 + b) * NN + i0 + tid] =
            s_rs[tid][0] + s_rs[tid][1] + s_rs[tid][2] + s_rs[tid][3];
}

// ---- kernel 3: field = (sum_jq part[jq]) / (sum_jq rs[jq] + 1e-8) ----
// 512 blocks x 256 thr, float2 per thread, 8 slabs.
__global__ __launch_bounds__(256) void reduce_kernel(
    const __hip_bfloat16* __restrict__ part,
    const float* __restrict__ part_rs,
    float* __restrict__ field)
{
    int t   = blockIdx.x * 256 + threadIdx.x;   // 131072 total
    int b   = t >> 16;
    int rem = t & 65535;
    int i   = rem >> 6;
    int d2  = (rem & 63) * 2;
    size_t ibase = (size_t)i * DD + d2;

    float s0 = 0.f, s1 = 0.f, rsum = 0.f;
    #pragma unroll
    for (int jq = 0; jq < 8; ++jq) {
        size_t slab = ((size_t)jq * 2 + b);
        unsigned int u = *(const unsigned int*)(part + slab * NN * DD + ibase);
        s0 += __uint_as_float(u << 16);
        s1 += __uint_as_float(u & 0xffff0000u);
        rsum += part_rs[slab * NN + i];
    }
    float inv = 1.0f / (rsum + 1e-8f);
    float2 o = {s0 * inv, s1 * inv};
    *(float2*)(field + ((size_t)b * NN + i) * DD + d2) = o;
}

// ---------------- launch ----------------
extern "C" void kernel_launch(void* const* d_in, const int* in_sizes, int n_in,
                              void* d_out, int out_size, void* d_ws, size_t ws_size,
                              hipStream_t stream) {
    const float* states = (const float*)d_in[0];
    const float* gates  = (const float*)d_in[1];
    const float* r_acc  = (const float*)d_in[2];
    const float* W_in   = (const float*)d_in[3];
    const float* W_out  = (const float*)d_in[4];
    const float* cond   = (const float*)d_in[5];

    float* field = (float*)d_out;                 // (2,1024,128)
    float* r_out = field + 2 * NN * DD;           // (2,1024,1024)

    char* ws = (char*)d_ws;
    __hip_bfloat16* M_bf    = (__hip_bfloat16*)ws;                   // 512 KB @ 0
    __hip_bfloat16* valT    = (__hip_bfloat16*)(ws + (512 << 10));   // 512 KB @ 512K
    __hip_bfloat16* part    = (__hip_bfloat16*)(ws + (1 << 20));     // 4 MB  @ 1M
    float*          part_rs = (float*)(ws + (5 << 20));              // 64 KB @ 5M

    hipLaunchKernelGGL(prep_kernel, dim3(4, 64, 2), dim3(64), 0, stream,
                       states, gates, W_in, W_out, M_bf, valT);
    hipLaunchKernelGGL(fused_kernel, dim3(8, 64, 2), dim3(256), 0, stream,
                       M_bf, valT, r_acc, gates, cond, r_out, part, part_rs);
    hipLaunchKernelGGL(reduce_kernel, dim3(512), dim3(256), 0, stream,
                       part, part_rs, field);
}